// Round 4
// baseline (192.660 us; speedup 1.0000x reference)
//
#include <hip/hip_runtime.h>
#include <hip/hip_bf16.h>
#include <math.h>

typedef __attribute__((ext_vector_type(8))) __bf16 bf16x8;
typedef __attribute__((ext_vector_type(4))) float f32x4;
typedef __attribute__((ext_vector_type(16))) float f32x16;
typedef __attribute__((ext_vector_type(4))) unsigned short us4;

#define DEVINL static __device__ __forceinline__

DEVINL unsigned short f2bf(float f) {
  union { float f; unsigned int u; } v; v.f = f;
  return (unsigned short)((v.u + 0x7FFFu + ((v.u >> 16) & 1u)) >> 16);  // RNE
}

// hardware bf16 convert; compiler fuses adjacent pairs into v_cvt_pk_bf16_f32
DEVINL unsigned short f2bf_hw(float f) {
  __bf16 h = (__bf16)f;
  union { __bf16 h; unsigned short u; } v; v.h = h;
  return v.u;
}

DEVINL unsigned pk2(float a, float b) {
  return (unsigned)f2bf_hw(a) | ((unsigned)f2bf_hw(b) << 16);
}

DEVINL f32x4 mfma16(bf16x8 a, bf16x8 b, f32x4 c) {
  return __builtin_amdgcn_mfma_f32_16x16x32_bf16(a, b, c, 0, 0, 0);
}
DEVINL f32x16 mfma32(bf16x8 a, bf16x8 b, f32x16 c) {
  return __builtin_amdgcn_mfma_f32_32x32x16_bf16(a, b, c, 0, 0, 0);
}

#define GLOAD16(GP, LP)                                                        \
  __builtin_amdgcn_global_load_lds(                                            \
      (const __attribute__((address_space(1))) void*)(GP),                     \
      (__attribute__((address_space(3))) void*)(LP), 16, 0, 0)

// problem constants
static constexpr int kB = 4, kT = 2048, kC = 1024, kH = 16, kD = 64;
static constexpr int kM = kB * kT;  // 8192

// ---------------------------------------------------------------- prep ----
__global__ void cvt_x_kernel(const float* __restrict__ x,
                             unsigned short* __restrict__ xb, int n4) {
  int stride = gridDim.x * blockDim.x;
  for (int i = blockIdx.x * blockDim.x + threadIdx.x; i < n4; i += stride) {
    float4 v = ((const float4*)x)[i];
    us4 o;
    o[0] = f2bf(v.x); o[1] = f2bf(v.y); o[2] = f2bf(v.z); o[3] = f2bf(v.w);
    ((us4*)xb)[i] = o;
  }
}

// W [K][N] f32  ->  WT [N][K] bf16
__global__ void transpose_w_kernel(const float* __restrict__ W,
                                   unsigned short* __restrict__ WT,
                                   int K, int N) {
  __shared__ float tile[32][33];
  int n0 = blockIdx.x * 32, k0 = blockIdx.y * 32;
  int tx = threadIdx.x, ty = threadIdx.y;
#pragma unroll
  for (int i = 0; i < 4; ++i)
    tile[ty + i * 8][tx] = W[(size_t)(k0 + ty + i * 8) * N + n0 + tx];
  __syncthreads();
#pragma unroll
  for (int i = 0; i < 4; ++i)
    WT[(size_t)(n0 + ty + i * 8) * K + k0 + tx] = f2bf(tile[tx][ty + i * 8]);
}

// transposed layout: cosT/sinT[d2][t], d2 in [0,32), t in [0,2048)
// -> epilogue loads 4 consecutive t as one float4
__global__ void rope_table_kernel(float* __restrict__ cosT,
                                  float* __restrict__ sinT) {
  int idx = blockIdx.x * blockDim.x + threadIdx.x;
  if (idx >= kT * 32) return;
  int d2 = idx >> 11, t = idx & 2047;
  double ang = (double)t * pow(10000.0, -(double)d2 / 32.0);
  cosT[idx] = (float)cos(ang);
  sinT[idx] = (float)sin(ang);
}

// ---------------------------------------------------------------- GEMM ----
// (frozen at round-3 state: 256x128 tile, BK=64, 8 waves, phase-split
// schedule, granule swizzle, counted vmcnt.  Three structures measured
// within noise of each other at ~640 TF; GEMM is locally converged.)
// EPI==0: f32 to Cout.  EPI==1: RoPE + scatter Q,K->(B,H,T,D), V->(B,H,D,T).
template <int EPI>
__global__ __launch_bounds__(512, 2) void gemm_bt_kernel(
    const unsigned short* __restrict__ A, const unsigned short* __restrict__ Bt,
    float* __restrict__ Cout, int Ndim, int Kdim,
    const float* __restrict__ cosT, const float* __restrict__ sinT,
    unsigned short* __restrict__ Qr, unsigned short* __restrict__ Kr,
    unsigned short* __restrict__ Vtg) {
  __shared__ unsigned short As[3][256 * 64];  // 96 KiB
  __shared__ unsigned short Bs[3][128 * 64];  // 48 KiB
  const int tid = threadIdx.x;
  const int wave = tid >> 6, lane = tid & 63;

  // T1: bijective XCD swizzle (nwg % 8 == 0 for both grids)
  const int nwg = gridDim.x * gridDim.y;
  const int lin = blockIdx.y * gridDim.x + blockIdx.x;
  const int wg = (lin & 7) * (nwg >> 3) + (lin >> 3);
  const int n0 = (wg % gridDim.x) * 128, m0 = (wg / gridDim.x) * 256;

  const int wr = wave >> 1, wc = wave & 1;  // 4M x 2N wave grid

  f32x4 acc[4][4] = {};

  const int fr = lane & 15;

  // stage: one load-instr covers 512 16B-blocks; block b = (row=b>>3, kb=b&7)
  // of a [rows][64] tile (128B rows, 8 granules).  LDS dest linear; global
  // source granule = kb ^ (row&7)  (involution).
  const int sblk = tid;               // block within load group (wave-contig)
  const int srow3 = sblk >> 3, skb = sblk & 7;
  const int sgran = (skb ^ (srow3 & 7)) << 3;  // halfword offset in row

  auto stageA = [&](int t, int l) {
    const int bb = t % 3;
    const int k0 = t << 6;
    const int row = (l << 6) + srow3;  // l*512 blocks = l*64 rows
    GLOAD16(A + (size_t)(m0 + row) * Kdim + k0 + sgran,
            &As[bb][(l * 512 + wave * 64) * 8]);
  };
  auto stageB = [&](int t, int l) {
    const int bb = t % 3;
    const int k0 = t << 6;
    const int row = (l << 6) + srow3;
    GLOAD16(Bt + (size_t)(n0 + row) * Kdim + k0 + sgran,
            &Bs[bb][(l * 512 + wave * 64) * 8]);
  };

  const int NT = Kdim >> 6;  // 16 for K=1024

  // prologue: tiles 0,1 in flight (12 loads), publish tile 0
  stageA(0, 0); stageA(0, 1); stageA(0, 2); stageA(0, 3);
  stageB(0, 0); stageB(0, 1);
  stageA(1, 0); stageA(1, 1); stageA(1, 2); stageA(1, 3);
  stageB(1, 0); stageB(1, 1);
  asm volatile("s_waitcnt vmcnt(6)" ::: "memory");
  __builtin_amdgcn_sched_barrier(0);
  __builtin_amdgcn_s_barrier();

  // read-side swizzled granule for phase p: (p*4 + (lane>>4)) ^ (lane&7);
  // frag rows = base + f*16 + fr -> row&7 == lane&7 (f-independent).
  const int rx = lane & 7, ku = lane >> 4;

  for (int t = 0; t < NT; ++t) {
    const int buf = t % 3;
    const unsigned char* Ab = (const unsigned char*)As[buf];
    const unsigned char* Bb = (const unsigned char*)Bs[buf];
    bf16x8 af[4], bfr[4];

    // ---------------- phase 0: k 0..31 ----------------
    {
      const int col = ((ku ^ rx) << 4);
#pragma unroll
      for (int f = 0; f < 4; ++f)
        af[f] = *(const bf16x8*)(Ab + (wr * 64 + f * 16 + fr) * 128 + col);
#pragma unroll
      for (int f = 0; f < 4; ++f)
        bfr[f] = *(const bf16x8*)(Bb + (wc * 64 + f * 16 + fr) * 128 + col);
    }
    if (t + 2 < NT) { stageA(t + 2, 0); stageA(t + 2, 1); stageB(t + 2, 0); }
    __builtin_amdgcn_s_barrier();
    asm volatile("s_waitcnt lgkmcnt(0)" ::: "memory");
    __builtin_amdgcn_sched_barrier(0);
    __builtin_amdgcn_s_setprio(1);
#pragma unroll
    for (int i = 0; i < 4; ++i)
#pragma unroll
      for (int j = 0; j < 4; ++j)
        acc[i][j] = mfma16(af[i], bfr[j], acc[i][j]);
    __builtin_amdgcn_s_setprio(0);
    __builtin_amdgcn_s_barrier();

    // ---------------- phase 1: k 32..63 ----------------
    {
      const int col = (((4 | ku) ^ rx) << 4);
#pragma unroll
      for (int f = 0; f < 4; ++f)
        af[f] = *(const bf16x8*)(Ab + (wr * 64 + f * 16 + fr) * 128 + col);
#pragma unroll
      for (int f = 0; f < 4; ++f)
        bfr[f] = *(const bf16x8*)(Bb + (wc * 64 + f * 16 + fr) * 128 + col);
    }
    if (t + 2 < NT) { stageA(t + 2, 2); stageA(t + 2, 3); stageB(t + 2, 1); }
    // counted wait once per K-tile: tile t+1 must be landed before the next
    // iteration's ds_reads; newer in-flight = tile t+2's 6 loads.
    if (t + 2 < NT) {
      asm volatile("s_waitcnt vmcnt(6)" ::: "memory");
    } else if (t + 1 < NT) {
      asm volatile("s_waitcnt vmcnt(0)" ::: "memory");
    }
    __builtin_amdgcn_sched_barrier(0);
    __builtin_amdgcn_s_barrier();
    asm volatile("s_waitcnt lgkmcnt(0)" ::: "memory");
    __builtin_amdgcn_sched_barrier(0);
    __builtin_amdgcn_s_setprio(1);
#pragma unroll
    for (int i = 0; i < 4; ++i)
#pragma unroll
      for (int j = 0; j < 4; ++j)
        acc[i][j] = mfma16(af[i], bfr[j], acc[i][j]);
    __builtin_amdgcn_s_setprio(0);
    __builtin_amdgcn_s_barrier();  // readiness barrier for tile t+1
  }

  // epilogue: C layout col = lane&15, row = (lane>>4)*4 + r   [m89]
  const int lr = (lane >> 4) * 4;
  const int fc = lane & 15;
  if (EPI == 0) {
#pragma unroll
    for (int i = 0; i < 4; ++i) {
      int mb = m0 + wr * 64 + i * 16 + lr;
#pragma unroll
      for (int j = 0; j < 4; ++j) {
        int n = n0 + wc * 64 + j * 16 + fc;
#pragma unroll
        for (int r = 0; r < 4; ++r)
          Cout[(size_t)(mb + r) * Ndim + n] = acc[i][j][r];
      }
    }
  } else {
#pragma unroll
    for (int i = 0; i < 4; ++i) {
      int mb = m0 + wr * 64 + i * 16 + lr;
      int b = mb >> 11, t0 = mb & 2047;
#pragma unroll
      for (int j = 0; j < 4; ++j) {
        int n = n0 + wc * 64 + j * 16 + fc;
        int sec = n >> 10;          // uniform across the wave (tile 128 wide)
        int c = n & 1023;
        int h = c >> 6, d = c & 63;
        size_t bh = (size_t)(b * 16 + h);
        if (sec == 2) {  // V -> (B,H,D,T), 4 t-consecutive bf16 = one 8B store
          us4 pk;
#pragma unroll
          for (int r = 0; r < 4; ++r) pk[r] = f2bf(acc[i][j][r]);
          *(us4*)&Vtg[(bh * 64 + d) * 2048 + t0] = pk;
        } else {         // Q/K with RoPE; pair partner lives in lane^1
          unsigned short* dst = (sec == 0) ? Qr : Kr;
          // transposed tables: one float4 covers r=0..3 (t0..t0+3)
          float4 c4 = *(const float4*)&cosT[(d >> 1) * 2048 + t0];
          float4 s4 = *(const float4*)&sinT[(d >> 1) * 2048 + t0];
          const float* cp = (const float*)&c4;
          const float* sp = (const float*)&s4;
#pragma unroll
          for (int r = 0; r < 4; ++r) {
            float v = acc[i][j][r];
            float pv = __shfl_xor(v, 1);
            float y = (d & 1) ? fmaf(pv, sp[r], v * cp[r])
                              : fmaf(v, cp[r], -pv * sp[r]);
            dst[(bh * 2048 + t0 + r) * 64 + d] = f2bf(y);
          }
        }
      }
    }
  }
}

// ----------------------------------------------------------- attention ----
// Round-4: TLP restructure.  Theory: per-tile wall ~4460 cyc vs per-wave
// MFMA 540 + softmax VALU ~700 cyc; at 2 waves/SIMD the softmax VALU and
// barrier/latency dead time can't be hidden.  Changes:
//  (a) seg-split: each wg handles ONE q-block (1024 wgs, dim3(8,128))
//      instead of two serially -> more, shorter wgs, dynamic packing;
//      mixed-length wgs interleave within an XCD (qblk = wg&15).
//  (b) __launch_bounds__(256,3): cap VGPR at 168 (est. live ~140) ->
//      3 blocks/CU = 3 waves/SIMD (LDS 32KB/block allows 5; VGPR limits).
// Core per-tile structure unchanged (swapped-QK^T in-register softmax,
// T12 cvt_pk+permlane, T13 defer-max, T5 setprio, XOR-swizzled staging).
__global__ __launch_bounds__(256, 3)
void attn_kernel(const unsigned short* __restrict__ Qr,
                 const unsigned short* __restrict__ Kr,
                 const unsigned short* __restrict__ Vtg,
                 unsigned short* __restrict__ Yb) {
  __shared__ unsigned short Ks[2][64 * 64];
  __shared__ unsigned short Vs[2][64 * 64];

  const int tid = threadIdx.x;
  const int wave = tid >> 6, lane = tid & 63;
  const int q31 = lane & 31, hi = lane >> 5;
  const int srow = lane >> 3;            // staging: row within 8-row segment
  const int sblk = (lane & 7) ^ srow;    // pre-swizzled source 16B block
  const int rswz = (lane & 7) << 4;      // read-side XOR ((row&7)<<4, row&7==lane&7)

  // XCD swizzle (bijective: 1024 wgs % 8 == 0): each XCD owns 8 whole heads;
  // qblk = wg&15 cycles within an XCD -> long/short wgs interleaved.
  int lin = blockIdx.y * 8 + blockIdx.x;
  int wg = (lin & 7) * 128 + (lin >> 3);
  const int qblk = wg & 15;
  const int bh = wg >> 4;

  const unsigned short* Qg = Qr + (size_t)bh * 2048 * 64;
  const unsigned short* Kg = Kr + (size_t)bh * 2048 * 64;
  const unsigned short* Vg = Vtg + (size_t)bh * 64 * 2048;

  const float c = 0.18033688f;   // (1/sqrt(64)) * log2(e)
  const float THR = 44.0f;       // defer-max threshold (raw domain ~ 8/c)

  auto stage = [&](int j, int bb) {
    int kv0s = j * 64;
#pragma unroll
    for (int o = 0; o < 2; ++o) {
      int s = o * 4 + wave;
      int row = s * 8 + srow;
      GLOAD16(Kg + ((size_t)(kv0s + row) * 64 + sblk * 8), &Ks[bb][s * 512]);
      GLOAD16(Vg + ((size_t)row * 2048 + kv0s + sblk * 8), &Vs[bb][s * 512]);
    }
  };

  const int qw = qblk * 128 + wave * 32;
  const int qg = qw + q31;
  const int NT = 2 * qblk + 2;

  // Q in regs: B-operand of QK^T (col=q=lane&31, k = ds*16 + hi*8 + i)
  bf16x8 qf[4];
#pragma unroll
  for (int ds = 0; ds < 4; ++ds)
    qf[ds] = *(const bf16x8*)&Qg[(size_t)qg * 64 + ds * 16 + hi * 8];

  float mrow = -1e30f, lrow = 0.f;
  f32x16 y0 = {}, y1 = {};   // Y^T: d = dm*32 + (r&3)+8*(r>>2)+4*hi, q=lane&31

  stage(0, 0);
  asm volatile("s_waitcnt vmcnt(0)" ::: "memory");
  __syncthreads();

  for (int t = 0; t < NT; ++t) {
    const int buf = t & 1;
    if (t + 1 < NT) stage(t + 1, buf ^ 1);  // prefetch overlaps compute
    const int kv0 = t * 64;

    if (kv0 <= qw + 31) {  // skip fully-masked wave-tiles
      // S^T = K Q  (2 kv-subtiles of 32; k = d = 64 -> 4 slices)
      f32x16 st[2] = {};
      __builtin_amdgcn_s_setprio(1);
#pragma unroll
      for (int sub = 0; sub < 2; ++sub) {
        const unsigned char* kbase =
            (const unsigned char*)Ks[buf] + (sub * 32 + q31) * 128;
#pragma unroll
        for (int ds = 0; ds < 4; ++ds) {
          bf16x8 af = *(const bf16x8*)(kbase + ((ds * 32 + hi * 16) ^ rswz));
          st[sub] = mfma32(af, qf[ds], st[sub]);
        }
      }
      __builtin_amdgcn_s_setprio(0);

      // causal mask (only diag-crossing tiles)
      if (kv0 + 63 > qw) {
#pragma unroll
        for (int sub = 0; sub < 2; ++sub)
#pragma unroll
          for (int r = 0; r < 16; ++r) {
            int kv = kv0 + sub * 32 + (r & 3) + 8 * (r >> 2) + 4 * hi;
            if (kv > qg) st[sub][r] = -1e30f;
          }
      }

      // row max: lane-local + 1 cross-half shfl
      float tm = st[0][0];
#pragma unroll
      for (int r = 1; r < 16; ++r) tm = fmaxf(tm, st[0][r]);
#pragma unroll
      for (int r = 0; r < 16; ++r) tm = fmaxf(tm, st[1][r]);
      tm = fmaxf(tm, __shfl_xor(tm, 32));

      if (!__all(tm <= mrow + THR)) {  // defer-max (T13)
        float mn = fmaxf(mrow, tm);
        float al = __builtin_amdgcn_exp2f((mrow - mn) * c);
        mrow = mn;
        lrow *= al;
#pragma unroll
        for (int r = 0; r < 16; ++r) { y0[r] *= al; y1[r] *= al; }
      }

      // P = exp2(s*c - m*c), packed bf16 pairs, in-register
      const float mc = mrow * c;
      float ps = 0.f;
      unsigned pkw[2][8];
#pragma unroll
      for (int sub = 0; sub < 2; ++sub)
#pragma unroll
        for (int j = 0; j < 8; ++j) {
          float pa = __builtin_amdgcn_exp2f(fmaf(st[sub][2 * j], c, -mc));
          float pb = __builtin_amdgcn_exp2f(fmaf(st[sub][2 * j + 1], c, -mc));
          ps += pa + pb;
          pkw[sub][j] = pk2(pa, pb);
        }
      ps += __shfl_xor(ps, 32);
      lrow += ps;

      // Y^T += V^T P^T : B-frags from permlane32_swap of packed pairs
      __builtin_amdgcn_s_setprio(1);
#pragma unroll
      for (int sub = 0; sub < 2; ++sub) {
#pragma unroll
        for (int ksl = 0; ksl < 2; ++ksl) {
          unsigned w0 = pkw[sub][ksl * 4 + 0], w2 = pkw[sub][ksl * 4 + 2];
          unsigned w1 = pkw[sub][ksl * 4 + 1], w3 = pkw[sub][ksl * 4 + 3];
          // swaps high half of op0 with low half of op1:
          // w0' = {w0.lo, w2.lo} ; w2' = {w0.hi, w2.hi}
          asm volatile("v_permlane32_swap_b32 %0, %1" : "+v"(w0), "+v"(w2));
          asm volatile("v_permlane32_swap_b32 %0, %1" : "+v"(w1), "+v"(w3));
          union { bf16x8 v; unsigned u[4]; } pf;
          pf.u[0] = w0; pf.u[1] = w1; pf.u[2] = w2; pf.u[3] = w3;
          const int cb = sub * 64 + ksl * 32 + hi * 16;
#pragma unroll
          for (int dm = 0; dm < 2; ++dm) {
            const int row = dm * 32 + q31;
            bf16x8 vf = *(const bf16x8*)((const unsigned char*)Vs[buf] +
                                         row * 128 + (cb ^ rswz));
            if (dm == 0) y0 = mfma32(vf, pf.v, y0);
            else         y1 = mfma32(vf, pf.v, y1);
          }
        }
      }
      __builtin_amdgcn_s_setprio(0);
    }

    __syncthreads();  // drains prefetch (vmcnt 0) + all waves done with buf
  }

  // epilogue: Y^T regs -> Yb (B,T,C); 4 consecutive d per us4 store
  const int b = bh >> 4, h = bh & 15;
  float inv = __builtin_amdgcn_rcpf(lrow);
  unsigned short* yrow = Yb + (size_t)(b * 2048 + qg) * 1024 + h * 64;
#pragma unroll
  for (int dm = 0; dm < 2; ++dm)
#pragma unroll
    for (int g = 0; g < 4; ++g) {
      us4 o;
#pragma unroll
      for (int e = 0; e < 4; ++e) {
        float yv = dm ? y1[g * 4 + e] : y0[g * 4 + e];
        o[e] = f2bf_hw(yv * inv);
      }
      *(us4*)&yrow[dm * 32 + g * 8 + hi * 4] = o;
    }
}

// ---------------------------------------------------------------- launch ----
extern "C" void kernel_launch(void* const* d_in, const int* in_sizes, int n_in,
                              void* d_out, int out_size, void* d_ws,
                              size_t ws_size, hipStream_t stream) {
  const float* x = (const float*)d_in[0];
  const float* Wa = (const float*)d_in[1];
  const float* Wp = (const float*)d_in[2];
  float* out = (float*)d_out;
  char* ws = (char*)d_ws;

  // workspace layout (bytes); xb aliases Yb (disjoint lifetimes)
  constexpr size_t OFF_WAT = 0;                       //  6291456: W_attn^T bf16
  constexpr size_t OFF_WPT = 6291456;                 //  2097152: W_proj^T bf16
  constexpr size_t OFF_COS = 8388608;                 //   262144
  constexpr size_t OFF_SIN = 8650752;                 //   262144
  constexpr size_t OFF_XB  = 8912896;                 // 16777216: x bf16 / y bf16
  constexpr size_t OFF_Q   = 25690112;                // 16777216 (B,H,T,D)
  constexpr size_t OFF_K   = 42467328;                // 16777216 (B,H,T,D)
  constexpr size_t OFF_V   = 59244544;                // 16777216 (B,H,D,T)

  unsigned short* WaT = (unsigned short*)(ws + OFF_WAT);
  unsigned short* WpT = (unsigned short*)(ws + OFF_WPT);
  float* cosT = (float*)(ws + OFF_COS);
  float* sinT = (float*)(ws + OFF_SIN);
  unsigned short* xb = (unsigned short*)(ws + OFF_XB);
  unsigned short* Yb = xb;  // alias: attention output reuses xb
  unsigned short* Qr = (unsigned short*)(ws + OFF_Q);
  unsigned short* Kr = (unsigned short*)(ws + OFF_K);
  unsigned short* Vt = (unsigned short*)(ws + OFF_V);

  // 1) prep
  cvt_x_kernel<<<2048, 256, 0, stream>>>(x, xb, kM * kC / 4);
  transpose_w_kernel<<<dim3(96, 32), dim3(32, 8), 0, stream>>>(Wa, WaT, 1024, 3072);
  transpose_w_kernel<<<dim3(32, 32), dim3(32, 8), 0, stream>>>(Wp, WpT, 1024, 1024);
  rope_table_kernel<<<256, 256, 0, stream>>>(cosT, sinT);

  // 2) qkv = x @ W_attn, fused RoPE + scatter (768 wgs = 3.0/CU)
  gemm_bt_kernel<1><<<dim3(24, 32), 512, 0, stream>>>(
      xb, WaT, nullptr, 3072, 1024, cosT, sinT, Qr, Kr, Vt);

  // 3) causal flash attention -> Yb (B,T,C) bf16  (1024 wgs, one q-block each)
  attn_kernel<<<dim3(8, 128), 256, 0, stream>>>(Qr, Kr, Vt, Yb);

  // 4) out = y @ W_proj (f32 out; 256 wgs = 1.0/CU)
  gemm_bt_kernel<0><<<dim3(8, 32), 512, 0, stream>>>(
      Yb, WpT, out, 1024, 1024, nullptr, nullptr, nullptr, nullptr, nullptr);
}

// Round 5
// 181.106 us; speedup vs baseline: 1.0638x; 1.0638x over previous
//
#include <hip/hip_runtime.h>
#include <hip/hip_bf16.h>
#include <math.h>

typedef __attribute__((ext_vector_type(8))) __bf16 bf16x8;
typedef __attribute__((ext_vector_type(4))) float f32x4;
typedef __attribute__((ext_vector_type(16))) float f32x16;
typedef __attribute__((ext_vector_type(4))) unsigned short us4;

#define DEVINL static __device__ __forceinline__

DEVINL unsigned short f2bf(float f) {
  union { float f; unsigned int u; } v; v.f = f;
  return (unsigned short)((v.u + 0x7FFFu + ((v.u >> 16) & 1u)) >> 16);  // RNE
}

// hardware bf16 convert; compiler fuses adjacent pairs into v_cvt_pk_bf16_f32
DEVINL unsigned short f2bf_hw(float f) {
  __bf16 h = (__bf16)f;
  union { __bf16 h; unsigned short u; } v; v.h = h;
  return v.u;
}

DEVINL unsigned pk2(float a, float b) {
  return (unsigned)f2bf_hw(a) | ((unsigned)f2bf_hw(b) << 16);
}

DEVINL f32x4 mfma16(bf16x8 a, bf16x8 b, f32x4 c) {
  return __builtin_amdgcn_mfma_f32_16x16x32_bf16(a, b, c, 0, 0, 0);
}
DEVINL f32x16 mfma32(bf16x8 a, bf16x8 b, f32x16 c) {
  return __builtin_amdgcn_mfma_f32_32x32x16_bf16(a, b, c, 0, 0, 0);
}

#define GLOAD16(GP, LP)                                                        \
  __builtin_amdgcn_global_load_lds(                                            \
      (const __attribute__((address_space(1))) void*)(GP),                     \
      (__attribute__((address_space(3))) void*)(LP), 16, 0, 0)

// problem constants
static constexpr int kB = 4, kT = 2048, kC = 1024, kH = 16, kD = 64;
static constexpr int kM = kB * kT;  // 8192

// ---------------------------------------------------------------- prep ----
// Merged prep: one launch instead of four (cvt_x | transpose Wa | transpose
// Wp | rope tables), split by blockIdx range.  Saves ~3 launch gaps; each
// sub-range keeps its original access pattern.
__global__ __launch_bounds__(256) void prep_kernel(
    const float* __restrict__ x, unsigned short* __restrict__ xb,
    const float* __restrict__ Wa, unsigned short* __restrict__ WaT,
    const float* __restrict__ Wp, unsigned short* __restrict__ WpT,
    float* __restrict__ cosT, float* __restrict__ sinT) {
  const int blk = blockIdx.x;
  if (blk < 2048) {
    // x f32 -> bf16 (grid-stride over 2M float4 groups)
    const int n4 = kM * kC / 4;
    for (int i = blk * 256 + threadIdx.x; i < n4; i += 2048 * 256) {
      float4 v = ((const float4*)x)[i];
      us4 o;
      o[0] = f2bf(v.x); o[1] = f2bf(v.y); o[2] = f2bf(v.z); o[3] = f2bf(v.w);
      ((us4*)xb)[i] = o;
    }
  } else if (blk < 2048 + 3072 + 1024) {
    // W [K][N] f32 -> WT [N][K=1024] bf16, 32x32 tiles (+1-pad LDS)
    __shared__ float tile[32][33];
    int t = blk - 2048;
    const float* W; unsigned short* WT; int N, bx, by;
    if (t < 3072) { W = Wa; WT = WaT; N = 3072; bx = t % 96; by = t / 96; }
    else { t -= 3072; W = Wp; WT = WpT; N = 1024; bx = t % 32; by = t / 32; }
    const int n0 = bx * 32, k0 = by * 32;
    const int tx = threadIdx.x & 31, ty = threadIdx.x >> 5;
#pragma unroll
    for (int i = 0; i < 4; ++i)
      tile[ty + i * 8][tx] = W[(size_t)(k0 + ty + i * 8) * N + n0 + tx];
    __syncthreads();
#pragma unroll
    for (int i = 0; i < 4; ++i)
      WT[(size_t)(n0 + ty + i * 8) * 1024 + k0 + tx] = f2bf(tile[tx][ty + i * 8]);
  } else {
    // RoPE tables, transposed layout cosT/sinT[d2][t]
    int idx = (blk - 6144) * 256 + threadIdx.x;  // 256 blocks -> kT*32
    int d2 = idx >> 11, t = idx & 2047;
    double ang = (double)t * pow(10000.0, -(double)d2 / 32.0);
    cosT[idx] = (float)cos(ang);
    sinT[idx] = (float)sin(ang);
  }
}

// ---------------------------------------------------------------- GEMM ----
// (frozen at round-3 state: 256x128 tile, BK=64, 8 waves, phase-split
// schedule, granule swizzle, counted vmcnt.  Three structures measured
// within noise of each other at ~640 TF; GEMM is locally converged.)
// EPI==0: f32 to Cout.  EPI==1: RoPE + scatter Q,K->(B,H,T,D), V->(B,H,D,T).
template <int EPI>
__global__ __launch_bounds__(512, 2) void gemm_bt_kernel(
    const unsigned short* __restrict__ A, const unsigned short* __restrict__ Bt,
    float* __restrict__ Cout, int Ndim, int Kdim,
    const float* __restrict__ cosT, const float* __restrict__ sinT,
    unsigned short* __restrict__ Qr, unsigned short* __restrict__ Kr,
    unsigned short* __restrict__ Vtg) {
  __shared__ unsigned short As[3][256 * 64];  // 96 KiB
  __shared__ unsigned short Bs[3][128 * 64];  // 48 KiB
  const int tid = threadIdx.x;
  const int wave = tid >> 6, lane = tid & 63;

  // T1: bijective XCD swizzle (nwg % 8 == 0 for both grids)
  const int nwg = gridDim.x * gridDim.y;
  const int lin = blockIdx.y * gridDim.x + blockIdx.x;
  const int wg = (lin & 7) * (nwg >> 3) + (lin >> 3);
  const int n0 = (wg % gridDim.x) * 128, m0 = (wg / gridDim.x) * 256;

  const int wr = wave >> 1, wc = wave & 1;  // 4M x 2N wave grid

  f32x4 acc[4][4] = {};

  const int fr = lane & 15;

  // stage: one load-instr covers 512 16B-blocks; block b = (row=b>>3, kb=b&7)
  // of a [rows][64] tile (128B rows, 8 granules).  LDS dest linear; global
  // source granule = kb ^ (row&7)  (involution).
  const int sblk = tid;               // block within load group (wave-contig)
  const int srow3 = sblk >> 3, skb = sblk & 7;
  const int sgran = (skb ^ (srow3 & 7)) << 3;  // halfword offset in row

  auto stageA = [&](int t, int l) {
    const int bb = t % 3;
    const int k0 = t << 6;
    const int row = (l << 6) + srow3;  // l*512 blocks = l*64 rows
    GLOAD16(A + (size_t)(m0 + row) * Kdim + k0 + sgran,
            &As[bb][(l * 512 + wave * 64) * 8]);
  };
  auto stageB = [&](int t, int l) {
    const int bb = t % 3;
    const int k0 = t << 6;
    const int row = (l << 6) + srow3;
    GLOAD16(Bt + (size_t)(n0 + row) * Kdim + k0 + sgran,
            &Bs[bb][(l * 512 + wave * 64) * 8]);
  };

  const int NT = Kdim >> 6;  // 16 for K=1024

  // prologue: tiles 0,1 in flight (12 loads), publish tile 0
  stageA(0, 0); stageA(0, 1); stageA(0, 2); stageA(0, 3);
  stageB(0, 0); stageB(0, 1);
  stageA(1, 0); stageA(1, 1); stageA(1, 2); stageA(1, 3);
  stageB(1, 0); stageB(1, 1);
  asm volatile("s_waitcnt vmcnt(6)" ::: "memory");
  __builtin_amdgcn_sched_barrier(0);
  __builtin_amdgcn_s_barrier();

  // read-side swizzled granule for phase p: (p*4 + (lane>>4)) ^ (lane&7);
  // frag rows = base + f*16 + fr -> row&7 == lane&7 (f-independent).
  const int rx = lane & 7, ku = lane >> 4;

  for (int t = 0; t < NT; ++t) {
    const int buf = t % 3;
    const unsigned char* Ab = (const unsigned char*)As[buf];
    const unsigned char* Bb = (const unsigned char*)Bs[buf];
    bf16x8 af[4], bfr[4];

    // ---------------- phase 0: k 0..31 ----------------
    {
      const int col = ((ku ^ rx) << 4);
#pragma unroll
      for (int f = 0; f < 4; ++f)
        af[f] = *(const bf16x8*)(Ab + (wr * 64 + f * 16 + fr) * 128 + col);
#pragma unroll
      for (int f = 0; f < 4; ++f)
        bfr[f] = *(const bf16x8*)(Bb + (wc * 64 + f * 16 + fr) * 128 + col);
    }
    if (t + 2 < NT) { stageA(t + 2, 0); stageA(t + 2, 1); stageB(t + 2, 0); }
    __builtin_amdgcn_s_barrier();
    asm volatile("s_waitcnt lgkmcnt(0)" ::: "memory");
    __builtin_amdgcn_sched_barrier(0);
    __builtin_amdgcn_s_setprio(1);
#pragma unroll
    for (int i = 0; i < 4; ++i)
#pragma unroll
      for (int j = 0; j < 4; ++j)
        acc[i][j] = mfma16(af[i], bfr[j], acc[i][j]);
    __builtin_amdgcn_s_setprio(0);
    __builtin_amdgcn_s_barrier();

    // ---------------- phase 1: k 32..63 ----------------
    {
      const int col = (((4 | ku) ^ rx) << 4);
#pragma unroll
      for (int f = 0; f < 4; ++f)
        af[f] = *(const bf16x8*)(Ab + (wr * 64 + f * 16 + fr) * 128 + col);
#pragma unroll
      for (int f = 0; f < 4; ++f)
        bfr[f] = *(const bf16x8*)(Bb + (wc * 64 + f * 16 + fr) * 128 + col);
    }
    if (t + 2 < NT) { stageA(t + 2, 2); stageA(t + 2, 3); stageB(t + 2, 1); }
    // counted wait once per K-tile: tile t+1 must be landed before the next
    // iteration's ds_reads; newer in-flight = tile t+2's 6 loads.
    if (t + 2 < NT) {
      asm volatile("s_waitcnt vmcnt(6)" ::: "memory");
    } else if (t + 1 < NT) {
      asm volatile("s_waitcnt vmcnt(0)" ::: "memory");
    }
    __builtin_amdgcn_sched_barrier(0);
    __builtin_amdgcn_s_barrier();
    asm volatile("s_waitcnt lgkmcnt(0)" ::: "memory");
    __builtin_amdgcn_sched_barrier(0);
    __builtin_amdgcn_s_setprio(1);
#pragma unroll
    for (int i = 0; i < 4; ++i)
#pragma unroll
      for (int j = 0; j < 4; ++j)
        acc[i][j] = mfma16(af[i], bfr[j], acc[i][j]);
    __builtin_amdgcn_s_setprio(0);
    __builtin_amdgcn_s_barrier();  // readiness barrier for tile t+1
  }

  // epilogue: C layout col = lane&15, row = (lane>>4)*4 + r   [m89]
  const int lr = (lane >> 4) * 4;
  const int fc = lane & 15;
  if (EPI == 0) {
#pragma unroll
    for (int i = 0; i < 4; ++i) {
      int mb = m0 + wr * 64 + i * 16 + lr;
#pragma unroll
      for (int j = 0; j < 4; ++j) {
        int n = n0 + wc * 64 + j * 16 + fc;
#pragma unroll
        for (int r = 0; r < 4; ++r)
          Cout[(size_t)(mb + r) * Ndim + n] = acc[i][j][r];
      }
    }
  } else {
#pragma unroll
    for (int i = 0; i < 4; ++i) {
      int mb = m0 + wr * 64 + i * 16 + lr;
      int b = mb >> 11, t0 = mb & 2047;
#pragma unroll
      for (int j = 0; j < 4; ++j) {
        int n = n0 + wc * 64 + j * 16 + fc;
        int sec = n >> 10;          // uniform across the wave (tile 128 wide)
        int c = n & 1023;
        int h = c >> 6, d = c & 63;
        size_t bh = (size_t)(b * 16 + h);
        if (sec == 2) {  // V -> (B,H,D,T), 4 t-consecutive bf16 = one 8B store
          us4 pk;
#pragma unroll
          for (int r = 0; r < 4; ++r) pk[r] = f2bf(acc[i][j][r]);
          *(us4*)&Vtg[(bh * 64 + d) * 2048 + t0] = pk;
        } else {         // Q/K with RoPE; pair partner lives in lane^1
          unsigned short* dst = (sec == 0) ? Qr : Kr;
          // transposed tables: one float4 covers r=0..3 (t0..t0+3)
          float4 c4 = *(const float4*)&cosT[(d >> 1) * 2048 + t0];
          float4 s4 = *(const float4*)&sinT[(d >> 1) * 2048 + t0];
          const float* cp = (const float*)&c4;
          const float* sp = (const float*)&s4;
#pragma unroll
          for (int r = 0; r < 4; ++r) {
            float v = acc[i][j][r];
            float pv = __shfl_xor(v, 1);
            float y = (d & 1) ? fmaf(pv, sp[r], v * cp[r])
                              : fmaf(v, cp[r], -pv * sp[r]);
            dst[(bh * 2048 + t0 + r) * 64 + d] = f2bf(y);
          }
        }
      }
    }
  }
}

// ----------------------------------------------------------- attention ----
// Round-5: restore round-3's BALANCED pairing (round-4 post-mortem: the
// seg-split destroyed static balance -> 20 us tail), and shrink the barrier
// domain: 2-wave blocks (128 thr) owning 64 q-rows, paired (c, 31-c) so
// every wg does exactly 33 tiles.  1024 wgs -> 4 independent blocks/CU
// (launch_bounds(128,2); LDS 32KB x4 = 128KB): 4 independent tile-streams
// per CU instead of 2 barrier-locked 4-wave blocks -> a block stalled on
// stage-drain no longer stops the other waves (m114 overlap).  Per-wave
// program unchanged (swapped-QK^T in-register softmax, T12 cvt_pk+permlane,
// T13 defer-max, T5 setprio, XOR-swizzled staging).
__global__ __launch_bounds__(128, 2)
void attn_kernel(const unsigned short* __restrict__ Qr,
                 const unsigned short* __restrict__ Kr,
                 const unsigned short* __restrict__ Vtg,
                 unsigned short* __restrict__ Yb) {
  __shared__ unsigned short Ks[2][64 * 64];
  __shared__ unsigned short Vs[2][64 * 64];

  const int tid = threadIdx.x;
  const int wave = tid >> 6, lane = tid & 63;
  const int q31 = lane & 31, hi = lane >> 5;
  const int srow = lane >> 3;            // staging: row within 8-row segment
  const int sblk = (lane & 7) ^ srow;    // pre-swizzled source 16B block
  const int rswz = (lane & 7) << 4;      // read-side XOR ((row&7)<<4, row&7==lane&7)

  // XCD swizzle (bijective: 1024 wgs % 8 == 0): each XCD owns 8 whole heads
  int lin = blockIdx.y * 8 + blockIdx.x;
  int wg = (lin & 7) * 128 + (lin >> 3);
  const int cpair = wg & 15;             // 64-row block pair: (cpair, 31-cpair)
  const int bh = wg >> 4;

  const unsigned short* Qg = Qr + (size_t)bh * 2048 * 64;
  const unsigned short* Kg = Kr + (size_t)bh * 2048 * 64;
  const unsigned short* Vg = Vtg + (size_t)bh * 64 * 2048;

  const float c = 0.18033688f;   // (1/sqrt(64)) * log2(e)
  const float THR = 44.0f;       // defer-max threshold (raw domain ~ 8/c)

  // 2 waves cover 16 segments (8 K + 8 V): 4 K-loads + 4 V-loads per wave
  auto stage = [&](int j, int bb) {
    int kv0s = j * 64;
#pragma unroll
    for (int o = 0; o < 4; ++o) {
      int s = o * 2 + wave;
      int row = s * 8 + srow;
      GLOAD16(Kg + ((size_t)(kv0s + row) * 64 + sblk * 8), &Ks[bb][s * 512]);
      GLOAD16(Vg + ((size_t)row * 2048 + kv0s + sblk * 8), &Vs[bb][s * 512]);
    }
  };

  for (int seg = 0; seg < 2; ++seg) {
    const int qb = seg ? (31 - cpair) : cpair;  // 64-row block index
    const int qw = qb * 64 + wave * 32;
    const int qg = qw + q31;
    const int NT = qb + 1;

    // Q in regs: B-operand of QK^T (col=q=lane&31, k = ds*16 + hi*8 + i)
    bf16x8 qf[4];
#pragma unroll
    for (int ds = 0; ds < 4; ++ds)
      qf[ds] = *(const bf16x8*)&Qg[(size_t)qg * 64 + ds * 16 + hi * 8];

    float mrow = -1e30f, lrow = 0.f;
    f32x16 y0 = {}, y1 = {};   // Y^T: d = dm*32 + (r&3)+8*(r>>2)+4*hi, q=lane&31

    stage(0, 0);
    asm volatile("s_waitcnt vmcnt(0)" ::: "memory");
    __syncthreads();

    for (int t = 0; t < NT; ++t) {
      const int buf = t & 1;
      if (t + 1 < NT) stage(t + 1, buf ^ 1);  // prefetch overlaps compute
      const int kv0 = t * 64;

      if (kv0 <= qw + 31) {  // skip fully-masked wave-tiles
        // S^T = K Q  (2 kv-subtiles of 32; k = d = 64 -> 4 slices)
        f32x16 st[2] = {};
        __builtin_amdgcn_s_setprio(1);
#pragma unroll
        for (int sub = 0; sub < 2; ++sub) {
          const unsigned char* kbase =
              (const unsigned char*)Ks[buf] + (sub * 32 + q31) * 128;
#pragma unroll
          for (int ds = 0; ds < 4; ++ds) {
            bf16x8 af = *(const bf16x8*)(kbase + ((ds * 32 + hi * 16) ^ rswz));
            st[sub] = mfma32(af, qf[ds], st[sub]);
          }
        }
        __builtin_amdgcn_s_setprio(0);

        // causal mask (only diag-crossing tiles)
        if (kv0 + 63 > qw) {
#pragma unroll
          for (int sub = 0; sub < 2; ++sub)
#pragma unroll
            for (int r = 0; r < 16; ++r) {
              int kv = kv0 + sub * 32 + (r & 3) + 8 * (r >> 2) + 4 * hi;
              if (kv > qg) st[sub][r] = -1e30f;
            }
        }

        // row max: lane-local + 1 cross-half shfl
        float tm = st[0][0];
#pragma unroll
        for (int r = 1; r < 16; ++r) tm = fmaxf(tm, st[0][r]);
#pragma unroll
        for (int r = 0; r < 16; ++r) tm = fmaxf(tm, st[1][r]);
        tm = fmaxf(tm, __shfl_xor(tm, 32));

        if (!__all(tm <= mrow + THR)) {  // defer-max (T13)
          float mn = fmaxf(mrow, tm);
          float al = __builtin_amdgcn_exp2f((mrow - mn) * c);
          mrow = mn;
          lrow *= al;
#pragma unroll
          for (int r = 0; r < 16; ++r) { y0[r] *= al; y1[r] *= al; }
        }

        // P = exp2(s*c - m*c), packed bf16 pairs, in-register
        const float mc = mrow * c;
        float ps = 0.f;
        unsigned pkw[2][8];
#pragma unroll
        for (int sub = 0; sub < 2; ++sub)
#pragma unroll
          for (int j = 0; j < 8; ++j) {
            float pa = __builtin_amdgcn_exp2f(fmaf(st[sub][2 * j], c, -mc));
            float pb = __builtin_amdgcn_exp2f(fmaf(st[sub][2 * j + 1], c, -mc));
            ps += pa + pb;
            pkw[sub][j] = pk2(pa, pb);
          }
        ps += __shfl_xor(ps, 32);
        lrow += ps;

        // Y^T += V^T P^T : B-frags from permlane32_swap of packed pairs
        __builtin_amdgcn_s_setprio(1);
#pragma unroll
        for (int sub = 0; sub < 2; ++sub) {
#pragma unroll
          for (int ksl = 0; ksl < 2; ++ksl) {
            unsigned w0 = pkw[sub][ksl * 4 + 0], w2 = pkw[sub][ksl * 4 + 2];
            unsigned w1 = pkw[sub][ksl * 4 + 1], w3 = pkw[sub][ksl * 4 + 3];
            // swaps high half of op0 with low half of op1:
            // w0' = {w0.lo, w2.lo} ; w2' = {w0.hi, w2.hi}
            asm volatile("v_permlane32_swap_b32 %0, %1" : "+v"(w0), "+v"(w2));
            asm volatile("v_permlane32_swap_b32 %0, %1" : "+v"(w1), "+v"(w3));
            union { bf16x8 v; unsigned u[4]; } pf;
            pf.u[0] = w0; pf.u[1] = w1; pf.u[2] = w2; pf.u[3] = w3;
            const int cb = sub * 64 + ksl * 32 + hi * 16;
#pragma unroll
            for (int dm = 0; dm < 2; ++dm) {
              const int row = dm * 32 + q31;
              bf16x8 vf = *(const bf16x8*)((const unsigned char*)Vs[buf] +
                                           row * 128 + (cb ^ rswz));
              if (dm == 0) y0 = mfma32(vf, pf.v, y0);
              else         y1 = mfma32(vf, pf.v, y1);
            }
          }
        }
        __builtin_amdgcn_s_setprio(0);
      }

      __syncthreads();  // drains prefetch (vmcnt 0) + both waves done with buf
    }

    // epilogue: Y^T regs -> Yb (B,T,C); 4 consecutive d per us4 store
    const int b = bh >> 4, h = bh & 15;
    float inv = __builtin_amdgcn_rcpf(lrow);
    unsigned short* yrow = Yb + (size_t)(b * 2048 + qg) * 1024 + h * 64;
#pragma unroll
    for (int dm = 0; dm < 2; ++dm)
#pragma unroll
      for (int g = 0; g < 4; ++g) {
        us4 o;
#pragma unroll
        for (int e = 0; e < 4; ++e) {
          float yv = dm ? y1[g * 4 + e] : y0[g * 4 + e];
          o[e] = f2bf_hw(yv * inv);
        }
        *(us4*)&yrow[dm * 32 + g * 8 + hi * 4] = o;
      }
  }
}

// ---------------------------------------------------------------- launch ----
extern "C" void kernel_launch(void* const* d_in, const int* in_sizes, int n_in,
                              void* d_out, int out_size, void* d_ws,
                              size_t ws_size, hipStream_t stream) {
  const float* x = (const float*)d_in[0];
  const float* Wa = (const float*)d_in[1];
  const float* Wp = (const float*)d_in[2];
  float* out = (float*)d_out;
  char* ws = (char*)d_ws;

  // workspace layout (bytes); xb aliases Yb (disjoint lifetimes)
  constexpr size_t OFF_WAT = 0;                       //  6291456: W_attn^T bf16
  constexpr size_t OFF_WPT = 6291456;                 //  2097152: W_proj^T bf16
  constexpr size_t OFF_COS = 8388608;                 //   262144
  constexpr size_t OFF_SIN = 8650752;                 //   262144
  constexpr size_t OFF_XB  = 8912896;                 // 16777216: x bf16 / y bf16
  constexpr size_t OFF_Q   = 25690112;                // 16777216 (B,H,T,D)
  constexpr size_t OFF_K   = 42467328;                // 16777216 (B,H,T,D)
  constexpr size_t OFF_V   = 59244544;                // 16777216 (B,H,D,T)

  unsigned short* WaT = (unsigned short*)(ws + OFF_WAT);
  unsigned short* WpT = (unsigned short*)(ws + OFF_WPT);
  float* cosT = (float*)(ws + OFF_COS);
  float* sinT = (float*)(ws + OFF_SIN);
  unsigned short* xb = (unsigned short*)(ws + OFF_XB);
  unsigned short* Yb = xb;  // alias: attention output reuses xb
  unsigned short* Qr = (unsigned short*)(ws + OFF_Q);
  unsigned short* Kr = (unsigned short*)(ws + OFF_K);
  unsigned short* Vt = (unsigned short*)(ws + OFF_V);

  // 1) prep (merged: cvt_x | transpose Wa | transpose Wp | rope tables)
  prep_kernel<<<2048 + 3072 + 1024 + 256, 256, 0, stream>>>(
      x, xb, Wa, WaT, Wp, WpT, cosT, sinT);

  // 2) qkv = x @ W_attn, fused RoPE + scatter (768 wgs = 3.0/CU)
  gemm_bt_kernel<1><<<dim3(24, 32), 512, 0, stream>>>(
      xb, WaT, nullptr, 3072, 1024, cosT, sinT, Qr, Kr, Vt);

  // 3) causal flash attention -> Yb (B,T,C) bf16
  //    (1024 wgs of 2 waves, balanced pairs, 4 blocks/CU)
  attn_kernel<<<dim3(8, 128), 128, 0, stream>>>(Qr, Kr, Vt, Yb);

  // 4) out = y @ W_proj (f32 out; 256 wgs = 1.0/CU)
  gemm_bt_kernel<0><<<dim3(8, 32), 512, 0, stream>>>(
      Yb, WpT, out, 1024, 1024, nullptr, nullptr, nullptr, nullptr, nullptr);
}